// Round 11
// baseline (93.434 us; speedup 1.0000x reference)
//
#include <hip/hip_runtime.h>

// Problem constants (from reference)
#define NF 10000
#define LL 100000

typedef float f32x4 __attribute__((ext_vector_type(4)));

constexpr int BC     = 64;                   // B*C
constexpr int NCHUNK = 32;                   // l-chunks per bc
constexpr int PCH    = LL / NCHUNK;          // 3125
constexpr int MBLK   = BC * NCHUNK;          // 2048
constexpr int BLOCK  = 256;

constexpr int PREP_BLOCKS = (BC * NF + 255) / 256;   // 2500

// workspace layout
constexpr size_t WS_ACC  = 0;     // double
constexpr size_t WS_DONE = 8;     // int
constexpr size_t WS_TBL  = 256;   // f32x4[BC*NF] = 10,240,000 B
constexpr size_t WS_NEED = WS_TBL + (size_t)BC * NF * 16;

// ---------- prep: elementwise pack (fgap, t_f) -> tbl[bc*NF+nf]; init counters ----------
__global__ __launch_bounds__(256) void prep_pack(
    const float2* __restrict__ i_f, const float2* __restrict__ t_f,
    f32x4* __restrict__ tbl, double* __restrict__ acc, int* __restrict__ done)
{
    if (blockIdx.x == 0 && threadIdx.x == 0) { *acc = 0.0; *done = 0; }
    const int e = blockIdx.x * 256 + threadIdx.x;
    if (e < BC * NF) {
        float2 iv = i_f[e];
        float2 tv = t_f[e];
        tbl[e] = (f32x4){iv.x - tv.x, iv.y - tv.y, tv.x, tv.y};
    }
}

// ---------- main: R1's exact loop body; packed-table gather; XCD-pinned bc ----------
__global__ __launch_bounds__(BLOCK) void k_main9(
    const float* __restrict__ i_s, const float* __restrict__ t_s,
    const int*  __restrict__ xi,  const float* __restrict__ ks,
    const f32x4* __restrict__ tbl,
    double* __restrict__ acc, int* __restrict__ done, float* __restrict__ out)
{
    // XCD x = blockIdx%8 owns bc in [8x, 8x+8): per-XCD table set = 8*160KB = 1.3MB (L2-fit)
    const int x     = blockIdx.x & 7;
    const int g     = (blockIdx.x >> 3) & 7;
    const int chunk = blockIdx.x >> 6;          // 0..31
    const int bc    = x * 8 + g;

    const int l0 = chunk * PCH;
    const int l1 = (l0 + PCH < LL) ? (l0 + PCH) : LL;

    const float2* __restrict__ isv = (const float2*)i_s + (size_t)bc * LL;
    const float2* __restrict__ tsv = (const float2*)t_s + (size_t)bc * LL;
    const f32x4*  __restrict__ tb  = tbl + (size_t)bc * NF;
    const int2*   __restrict__ xiv = (const int2*)xi;
    const float2* __restrict__ ksv = (const float2*)ks;

    float sum = 0.f;
    for (int l = l0 + (int)threadIdx.x; l < l1; l += BLOCK) {
        float2 si = isv[l];
        float2 st = tsv[l];
        float gr = si.x - st.x;
        float gi = si.y - st.y;

        float2 k = ksv[l];
        if (!(k.x > 0.f) && !(k.y > 0.f)) {
            int2 idx = xiv[l];
            f32x4 r0 = tb[idx.x];   // (f0r, f0i, tf0r, tf0i)
            f32x4 r1 = tb[idx.y];   // (f1r, f1i, tf1r, tf1i)
            // corr = cmul_conj(f0,tf1) + cmul_conj(tf0,f1)
            gr -= r0.x * r1.z + r0.y * r1.w + r0.z * r1.x + r0.w * r1.y;
            gi -= r0.y * r1.z - r0.x * r1.w + r0.w * r1.x - r0.z * r1.y;
        }
        sum += gr * gr + gi * gi;
    }

    // wave-level reduce (64 lanes)
    #pragma unroll
    for (int off = 32; off; off >>= 1)
        sum += __shfl_down(sum, off, 64);

    __shared__ float wsum[BLOCK / 64];
    const int lane = threadIdx.x & 63;
    const int wid  = threadIdx.x >> 6;
    if (lane == 0) wsum[wid] = sum;
    __syncthreads();
    if (threadIdx.x == 0) {
        float t = wsum[0] + wsum[1] + wsum[2] + wsum[3];
        atomicAdd(acc, (double)t);
        __threadfence();
        int prev = atomicAdd(done, 1);
        if (prev == MBLK - 1) {
            __threadfence();
            double total = atomicAdd(acc, 0.0);
            out[0] = (float)(total / (double)((size_t)BC * LL));
        }
    }
}

// ---------- fallback (round-1 kernel) if workspace too small ----------
constexpr int FCHUNKS = 32;
constexpr int FCHUNK  = (LL + FCHUNKS - 1) / FCHUNKS;

__global__ __launch_bounds__(256) void mse_fallback(
    const float* __restrict__ i_f, const float* __restrict__ i_s,
    const float* __restrict__ t_f, const float* __restrict__ t_s,
    const int*  __restrict__ xi,  const float* __restrict__ ks,
    double* __restrict__ acc)
{
    const int bc    = blockIdx.x / FCHUNKS;
    const int chunk = blockIdx.x % FCHUNKS;
    const int l0 = chunk * FCHUNK;
    const int l1 = (l0 + FCHUNK < LL) ? (l0 + FCHUNK) : LL;

    const float2* isv = (const float2*)i_s + (size_t)bc * LL;
    const float2* tsv = (const float2*)t_s + (size_t)bc * LL;
    const float2* ifv = (const float2*)i_f + (size_t)bc * NF;
    const float2* tfv = (const float2*)t_f + (size_t)bc * NF;
    const int2*   xiv = (const int2*)xi;
    const float2* ksv = (const float2*)ks;

    float sum = 0.f;
    for (int l = l0 + (int)threadIdx.x; l < l1; l += 256) {
        float2 si = isv[l], st = tsv[l];
        float gr = si.x - st.x, gi = si.y - st.y;
        float2 k = ksv[l];
        if (!(k.x > 0.f) && !(k.y > 0.f)) {
            int2 idx = xiv[l];
            float2 tf0 = tfv[idx.x], if0 = ifv[idx.x];
            float2 tf1 = tfv[idx.y], if1 = ifv[idx.y];
            float f0r = if0.x - tf0.x, f0i = if0.y - tf0.y;
            float f1r = if1.x - tf1.x, f1i = if1.y - tf1.y;
            gr -= f0r * tf1.x + f0i * tf1.y;
            gi -= f0i * tf1.x - f0r * tf1.y;
            gr -= tf0.x * f1r + tf0.y * f1i;
            gi -= tf0.y * f1r - tf0.x * f1i;
        }
        sum += gr * gr + gi * gi;
    }
    #pragma unroll
    for (int off = 32; off; off >>= 1) sum += __shfl_down(sum, off, 64);
    __shared__ float ws[4];
    const int lane = threadIdx.x & 63, wwid = threadIdx.x >> 6;
    if (lane == 0) ws[wwid] = sum;
    __syncthreads();
    if (threadIdx.x == 0) {
        float t = ws[0] + ws[1] + ws[2] + ws[3];
        atomicAdd(acc, (double)t);
    }
}

__global__ void mse_finalize(const double* __restrict__ acc, float* __restrict__ out)
{
    out[0] = (float)(acc[0] / (double)((size_t)BC * LL));
}

extern "C" void kernel_launch(void* const* d_in, const int* in_sizes, int n_in,
                              void* d_out, int out_size, void* d_ws, size_t ws_size,
                              hipStream_t stream)
{
    const float* i_f = (const float*)d_in[0];
    const float* i_s = (const float*)d_in[1];
    const float* t_f = (const float*)d_in[2];
    const float* t_s = (const float*)d_in[3];
    const int*   xi  = (const int*)d_in[4];
    const float* ks  = (const float*)d_in[5];
    float* out = (float*)d_out;

    char* ws = (char*)d_ws;
    double* acc  = (double*)(ws + WS_ACC);
    int*    done = (int*)(ws + WS_DONE);

    if (ws_size >= WS_NEED) {
        f32x4* tbl = (f32x4*)(ws + WS_TBL);
        prep_pack<<<PREP_BLOCKS, 256, 0, stream>>>(
            (const float2*)i_f, (const float2*)t_f, tbl, acc, done);
        k_main9<<<MBLK, BLOCK, 0, stream>>>(
            i_s, t_s, xi, ks, tbl, acc, done, out);
    } else {
        (void)hipMemsetAsync(ws, 0, 16, stream);
        mse_fallback<<<BC * FCHUNKS, 256, 0, stream>>>(
            i_f, i_s, t_f, t_s, xi, ks, acc);
        mse_finalize<<<1, 1, 0, stream>>>(acc, out);
    }
}